// Round 9
// baseline (233.135 us; speedup 1.0000x reference)
//
#include <hip/hip_runtime.h>
#include <hip/hip_bf16.h>

#define D_MODEL 1024
#define D_STATE 16
#define DT_RANK 64
#define SEQ 2048
#define BATCH 2
#define M_TOTAL 4096
#define CHUNKS 64
#define CLEN 32

typedef __bf16 bf16x8 __attribute__((ext_vector_type(8)));
typedef float f32x4 __attribute__((ext_vector_type(4)));

__device__ __forceinline__ unsigned short f2bf(float f) {
    union { float f; unsigned int u; } v; v.f = f;
    unsigned int r = v.u + 0x7FFFu + ((v.u >> 16) & 1u);
    return (unsigned short)(r >> 16);
}
__device__ __forceinline__ float bf2f(unsigned short u) {
    union { unsigned int i; float f; } v; v.i = ((unsigned int)u) << 16; return v.f;
}
__device__ __forceinline__ void gload16(const void* g, void* l) {
    __builtin_amdgcn_global_load_lds(
        (const __attribute__((address_space(1))) unsigned int*)g,
        (__attribute__((address_space(3))) unsigned int*)l, 16, 0, 0);
}

// ---------- fused setup ----------
// blocks: [0,4096) x->bf16 | [4096,5120) w_in->bf16 | [5120,6144) w_in^T->bt
//         [6144,6400) wxT (64x1024) | [6400,6528) wxBC (32x1024) | [6528,6592) aneg
__global__ void __launch_bounds__(256) k_setup(const float* __restrict__ x,
                                               const float* __restrict__ win,
                                               const float* __restrict__ wx,
                                               const float* __restrict__ alog,
                                               unsigned short* __restrict__ xb,
                                               unsigned short* __restrict__ wib,
                                               unsigned short* __restrict__ bt,
                                               unsigned short* __restrict__ wxT,
                                               unsigned short* __restrict__ wxBC,
                                               float* __restrict__ aneg) {
    __shared__ float tile[32][33];
    int blk = blockIdx.x;
    int t = threadIdx.x;
    if (blk < 4096) {
        int i = blk * 256 + t;
        float4 v = reinterpret_cast<const float4*>(x)[i];
        ushort4 o;
        o.x = f2bf(v.x); o.y = f2bf(v.y); o.z = f2bf(v.z); o.w = f2bf(v.w);
        reinterpret_cast<ushort4*>(xb)[i] = o;
    } else if (blk < 5120) {
        int i = (blk - 4096) * 256 + t;
        float4 v = reinterpret_cast<const float4*>(win)[i];
        ushort4 o;
        o.x = f2bf(v.x); o.y = f2bf(v.y); o.z = f2bf(v.z); o.w = f2bf(v.w);
        reinterpret_cast<ushort4*>(wib)[i] = o;
    } else if (blk < 6144) {
        int blk2 = blk - 5120;
        int bx = blk2 & 31, by = blk2 >> 5;
        int tx = t & 31, ty = t >> 5;
        int xc = bx * 32 + tx;
#pragma unroll
        for (int j = 0; j < 4; j++)
            tile[ty + 8 * j][tx] = win[(by * 32 + ty + 8 * j) * D_MODEL + xc];
        __syncthreads();
        int x2 = by * 32 + tx;
#pragma unroll
        for (int j = 0; j < 4; j++)
            bt[(bx * 32 + ty + 8 * j) * D_MODEL + x2] = f2bf(tile[tx][ty + 8 * j]);
    } else if (blk < 6400) {  // wxT rows 0..63 (dt_low cols of w_x)
        int idx = (blk - 6144) * 256 + t;
        int e = idx & 1023, p = idx >> 10;
        wxT[p * D_MODEL + e] = f2bf(wx[e * 96 + p]);
    } else if (blk < 6528) {  // wxBC[p][e] = w_x[e][64+p], p<32
        int idx = (blk - 6400) * 256 + t;
        int e = idx & 1023, p = idx >> 10;
        wxBC[p * D_MODEL + e] = f2bf(wx[e * 96 + 64 + p]);
    } else {
        int i = (blk - 6528) * 256 + t;
        if (i < D_MODEL * D_STATE) aneg[i] = -expf(alog[i]);
    }
}

// ---------- prep GEMM: Cp[ks*64+p][d] partials of (w_x[:, :64]^T @ w_in) ----------
__global__ void __launch_bounds__(256) k_prepgemm(const unsigned short* __restrict__ wxT,
                                                  const unsigned short* __restrict__ wib,
                                                  float* __restrict__ Cp) {
    __shared__ unsigned short sA[2][64 * 32];
    __shared__ unsigned short sB[2][128 * 32];
    int bid = blockIdx.x;  // 32 = 8 n x 4 ksplit
    int n0 = (bid & 7) * 128;
    int ks = bid >> 3;
    int kbase = ks * 256;
    int t = threadIdx.x;
    int lane = t & 63;
    int w = t >> 6;
    int c = lane & 15, q = lane >> 4;

    const unsigned short* ga = wxT + (t >> 2) * D_MODEL + (t & 3) * 8 + kbase;
    const unsigned short* gb = wib + (n0 + (t >> 2)) * D_MODEL + (t & 3) * 8 + kbase;

    f32x4 acc[4][2] = {};
    {
        char* la = (char*)&sA[0][0] + w * 1024;
        char* lb = (char*)&sB[0][0] + w * 1024;
        gload16(ga, la);
        gload16(gb, lb);
        gload16(gb + 64 * D_MODEL, lb + 4096);
    }
    int cur = 0;
    for (int it = 0; it < 8; it++) {
        __syncthreads();
        if (it + 1 < 8) {
            int kn = (it + 1) * 32;
            char* la = (char*)&sA[cur ^ 1][0] + w * 1024;
            char* lb = (char*)&sB[cur ^ 1][0] + w * 1024;
            gload16(ga + kn, la);
            gload16(gb + kn, lb);
            gload16(gb + 64 * D_MODEL + kn, lb + 4096);
        }
        bf16x8 af[4], bfr[2];
#pragma unroll
        for (int i = 0; i < 4; i++)
            af[i] = *reinterpret_cast<const bf16x8*>(&sA[cur][(i * 16 + c) * 32 + q * 8]);
#pragma unroll
        for (int j = 0; j < 2; j++)
            bfr[j] = *reinterpret_cast<const bf16x8*>(&sB[cur][(w * 32 + j * 16 + c) * 32 + q * 8]);
#pragma unroll
        for (int i = 0; i < 4; i++)
#pragma unroll
            for (int j = 0; j < 2; j++)
                acc[i][j] = __builtin_amdgcn_mfma_f32_16x16x32_bf16(af[i], bfr[j], acc[i][j], 0, 0, 0);
        cur ^= 1;
    }
#pragma unroll
    for (int i = 0; i < 4; i++) {
        int p = i * 16 + q * 4;
#pragma unroll
        for (int j = 0; j < 2; j++) {
            int d = n0 + w * 32 + j * 16 + c;
#pragma unroll
            for (int r = 0; r < 4; r++)
                Cp[(ks * 64 + p + r) * D_MODEL + d] = acc[i][j][r];
        }
    }
}

// ---------- prep reduce: Tt[p][d] = sum_ks Cp ----------
__global__ void __launch_bounds__(256) k_prepreduce(const float* __restrict__ Cp,
                                                    float* __restrict__ Tt) {
    int idx = blockIdx.x * 256 + threadIdx.x;  // 64*1024
    int d = idx & 1023;
    int p = idx >> 10;
    Tt[p * D_MODEL + d] = Cp[p * D_MODEL + d] + Cp[(64 + p) * D_MODEL + d] +
                          Cp[(128 + p) * D_MODEL + d] + Cp[(192 + p) * D_MODEL + d];
}

// ---------- prep2: bt rows 1024..2047 = (Tt^T @ w_dt)^T bf16 ----------
__global__ void __launch_bounds__(256) k_prep2(const float* __restrict__ wdt,
                                               const float* __restrict__ Tt,
                                               unsigned short* __restrict__ bt) {
    __shared__ float sw[DT_RANK][8];
    int m0 = blockIdx.x * 8;
    int tid = threadIdx.x;
    for (int s = tid; s < DT_RANK * 8; s += 256) {
        int r = s >> 3, rr = s & 7;
        sw[r][rr] = wdt[r * D_MODEL + m0 + rr];
    }
    __syncthreads();
    float acc[8][4] = {};
    for (int r = 0; r < DT_RANK; r++) {
        float tv0 = Tt[r * D_MODEL + tid];
        float tv1 = Tt[r * D_MODEL + tid + 256];
        float tv2 = Tt[r * D_MODEL + tid + 512];
        float tv3 = Tt[r * D_MODEL + tid + 768];
#pragma unroll
        for (int rr = 0; rr < 8; rr++) {
            float wv = sw[r][rr];
            acc[rr][0] = fmaf(wv, tv0, acc[rr][0]);
            acc[rr][1] = fmaf(wv, tv1, acc[rr][1]);
            acc[rr][2] = fmaf(wv, tv2, acc[rr][2]);
            acc[rr][3] = fmaf(wv, tv3, acc[rr][3]);
        }
    }
#pragma unroll
    for (int rr = 0; rr < 8; rr++)
#pragma unroll
        for (int i = 0; i < 4; i++)
            bt[(D_MODEL + m0 + rr) * D_MODEL + tid + i * 256] = f2bf(acc[rr][i]);
}

// ---------- big GEMM: 128x128 tile, BK=64, dbuf, XOR-swizzled LDS, grid 512 (2/CU) ----------
__global__ void __launch_bounds__(256) k_gemm_big(const unsigned short* __restrict__ xb,
                                                  const unsigned short* __restrict__ bt,
                                                  const float* __restrict__ bdt,
                                                  unsigned short* __restrict__ xinb,
                                                  unsigned short* __restrict__ dtb) {
    __shared__ unsigned short sA[2][128 * 64];
    __shared__ unsigned short sB[2][128 * 64];
    int bid = blockIdx.x;
    int m0 = (bid & 31) * 128;
    int nt = bid >> 5;  // 0..15
    int n0 = nt * 128;
    int t = threadIdx.x;
    int lane = t & 63;
    int w = t >> 6;
    int wm = (w >> 1) * 64, wn = (w & 1) * 64;
    int c = lane & 15, q = lane >> 4;

    const unsigned short* gA[4];
    const unsigned short* gB[4];
#pragma unroll
    for (int L = 0; L < 4; L++) {
        int s = L * 256 + t;
        int row = s >> 3, ch = (s & 7) ^ (row & 7);
        gA[L] = xb + (m0 + row) * D_MODEL + ch * 8;
        gB[L] = bt + (n0 + row) * D_MODEL + ch * 8;
    }

    f32x4 acc[4][4] = {};
    {
        char* la = (char*)&sA[0][0] + w * 1024;
        char* lb = (char*)&sB[0][0] + w * 1024;
#pragma unroll
        for (int L = 0; L < 4; L++) {
            gload16(gA[L], la + L * 4096);
            gload16(gB[L], lb + L * 4096);
        }
    }
    int cur = 0;
    for (int it = 0; it < 16; it++) {
        __syncthreads();
        if (it + 1 < 16) {
            int kn = (it + 1) * 64;
            char* la = (char*)&sA[cur ^ 1][0] + w * 1024;
            char* lb = (char*)&sB[cur ^ 1][0] + w * 1024;
#pragma unroll
            for (int L = 0; L < 4; L++) {
                gload16(gA[L] + kn, la + L * 4096);
                gload16(gB[L] + kn, lb + L * 4096);
            }
        }
#pragma unroll
        for (int kk = 0; kk < 2; kk++) {
            int perm = (((kk << 2) | q) ^ (c & 7)) << 3;
            bf16x8 af[4], bfr[4];
#pragma unroll
            for (int i = 0; i < 4; i++)
                af[i] = *reinterpret_cast<const bf16x8*>(&sA[cur][(wm + i * 16 + c) * 64 + perm]);
#pragma unroll
            for (int j = 0; j < 4; j++)
                bfr[j] = *reinterpret_cast<const bf16x8*>(&sB[cur][(wn + j * 16 + c) * 64 + perm]);
#pragma unroll
            for (int i = 0; i < 4; i++)
#pragma unroll
                for (int j = 0; j < 4; j++)
                    acc[i][j] = __builtin_amdgcn_mfma_f32_16x16x32_bf16(af[i], bfr[j], acc[i][j], 0, 0, 0);
        }
        cur ^= 1;
    }

    if (nt < 8) {
#pragma unroll
        for (int i = 0; i < 4; i++) {
            int row = m0 + wm + i * 16 + q * 4;
#pragma unroll
            for (int j = 0; j < 4; j++) {
                int col = n0 + wn + j * 16 + c;
#pragma unroll
                for (int r = 0; r < 4; r++)
                    xinb[(row + r) * D_MODEL + col] = f2bf(acc[i][j][r]);
            }
        }
    } else {
#pragma unroll
        for (int i = 0; i < 4; i++) {
            int row = m0 + wm + i * 16 + q * 4;
#pragma unroll
            for (int j = 0; j < 4; j++) {
                int dcol = n0 + wn + j * 16 + c - D_MODEL;
                float bv = bdt[dcol];
#pragma unroll
                for (int r = 0; r < 4; r++) {
                    float xv = acc[i][j][r] + bv;
                    float sp = fmaxf(xv, 0.f) + __logf(1.f + __expf(-fabsf(xv)));
                    dtb[(row + r) * D_MODEL + dcol] = f2bf(sp * 0.099f + 0.001f);
                }
            }
        }
    }
}

// ---------- winp + BC: bc[m][0:32] = x_in @ w_x[:,64:96]; winp[m,n] = B*sum(dt*u*A) ----------
__global__ void __launch_bounds__(256) k_winp(const unsigned short* __restrict__ dtb,
                                              const unsigned short* __restrict__ xinb,
                                              const float* __restrict__ aneg,
                                              const unsigned short* __restrict__ wxBC,
                                              float* __restrict__ bc,
                                              float* __restrict__ winp) {
    __shared__ float r0[16][17], r1[16][17];
    __shared__ float sbc[2][16][33];
    int m = blockIdx.x * 2;
    int tid = threadIdx.x;
    int n = tid & 15, strip = tid >> 4;
    float a0 = 0.f, a1 = 0.f;
    float b00 = 0.f, b01 = 0.f, b10 = 0.f, b11 = 0.f;
    int d0 = strip * 64;
    for (int dd = 0; dd < 64; dd += 4) {
        int d = d0 + dd;
        ushort4 t0 = *reinterpret_cast<const ushort4*>(dtb + m * D_MODEL + d);
        ushort4 u0 = *reinterpret_cast<const ushort4*>(xinb + m * D_MODEL + d);
        ushort4 t1 = *reinterpret_cast<const ushort4*>(dtb + (m + 1) * D_MODEL + d);
        ushort4 u1 = *reinterpret_cast<const ushort4*>(xinb + (m + 1) * D_MODEL + d);
        ushort4 wl = *reinterpret_cast<const ushort4*>(wxBC + n * D_MODEL + d);
        ushort4 wh = *reinterpret_cast<const ushort4*>(wxBC + (n + 16) * D_MODEL + d);
        float uu0[4] = {bf2f(u0.x), bf2f(u0.y), bf2f(u0.z), bf2f(u0.w)};
        float uu1[4] = {bf2f(u1.x), bf2f(u1.y), bf2f(u1.z), bf2f(u1.w)};
        float tt0[4] = {bf2f(t0.x), bf2f(t0.y), bf2f(t0.z), bf2f(t0.w)};
        float tt1[4] = {bf2f(t1.x), bf2f(t1.y), bf2f(t1.z), bf2f(t1.w)};
        float wwl[4] = {bf2f(wl.x), bf2f(wl.y), bf2f(wl.z), bf2f(wl.w)};
        float wwh[4] = {bf2f(wh.x), bf2f(wh.y), bf2f(wh.z), bf2f(wh.w)};
#pragma unroll
        for (int e = 0; e < 4; e++) {
            float av = aneg[(d + e) * 16 + n];
            a0 = fmaf(tt0[e] * uu0[e], av, a0);
            a1 = fmaf(tt1[e] * uu1[e], av, a1);
            b00 = fmaf(uu0[e], wwl[e], b00);
            b01 = fmaf(uu0[e], wwh[e], b01);
            b10 = fmaf(uu1[e], wwl[e], b10);
            b11 = fmaf(uu1[e], wwh[e], b11);
        }
    }
    r0[strip][n] = a0; r1[strip][n] = a1;
    sbc[0][strip][n] = b00; sbc[0][strip][n + 16] = b01;
    sbc[1][strip][n] = b10; sbc[1][strip][n + 16] = b11;
    __syncthreads();
    for (int s = 8; s > 0; s >>= 1) {
        if (strip < s) {
            r0[strip][n] += r0[strip + s][n];
            r1[strip][n] += r1[strip + s][n];
            sbc[0][strip][n] += sbc[0][strip + s][n];
            sbc[0][strip][n + 16] += sbc[0][strip + s][n + 16];
            sbc[1][strip][n] += sbc[1][strip + s][n];
            sbc[1][strip][n + 16] += sbc[1][strip + s][n + 16];
        }
        __syncthreads();
    }
    if (tid < 32) bc[m * 32 + tid] = sbc[0][0][tid];
    else if (tid < 64) bc[(m + 1) * 32 + (tid - 32)] = sbc[1][0][tid - 32];
    if (tid < 16) winp[m * 16 + n] = sbc[0][0][n] * r0[0][n];
    else if (tid < 32) winp[(m + 1) * 16 + n] = sbc[1][0][n] * r1[0][n];
}

// ---------- scan phase 1: chunk-local scan -> h_loc, dtsum (vector staging) ----------
__global__ void __launch_bounds__(256) k_scan1(const unsigned short* __restrict__ dtb,
                                               const float* __restrict__ winp,
                                               const float* __restrict__ aneg,
                                               float* __restrict__ h_loc,
                                               float* __restrict__ dtsum) {
    __shared__ unsigned short s_dt[16][256];
    __shared__ float s_w[16][16];
    int dc = blockIdx.x & 3;
    int c = (blockIdx.x >> 2) & (CHUNKS - 1);
    int b = blockIdx.x >> 8;
    int tid = threadIdx.x;
    int d = dc * 256 + tid;
    float Ad[16];
    const float4* ar = reinterpret_cast<const float4*>(aneg + d * 16);
#pragma unroll
    for (int j = 0; j < 4; j++) {
        float4 a4 = ar[j];
        Ad[4 * j + 0] = a4.x; Ad[4 * j + 1] = a4.y;
        Ad[4 * j + 2] = a4.z; Ad[4 * j + 3] = a4.w;
    }
    float h[16];
#pragma unroll
    for (int n = 0; n < 16; n++) h[n] = 0.f;
    float dts = 0.f;

    int r8 = tid >> 5, col8 = (tid & 31) * 8;
    for (int t0 = 0; t0 < CLEN; t0 += 16) {
        __syncthreads();
        int rowbase = b * SEQ + c * CLEN + t0;
        *reinterpret_cast<uint4*>(&s_dt[r8][col8]) =
            *reinterpret_cast<const uint4*>(dtb + (rowbase + r8) * D_MODEL + dc * 256 + col8);
        *reinterpret_cast<uint4*>(&s_dt[8 + r8][col8]) =
            *reinterpret_cast<const uint4*>(dtb + (rowbase + 8 + r8) * D_MODEL + dc * 256 + col8);
        {
            int r = tid >> 4, n = tid & 15;
            s_w[r][n] = winp[(rowbase + r) * 16 + n];
        }
        __syncthreads();
        for (int r = 0; r < 16; r++) {
            float dtv = bf2f(s_dt[r][tid]);
            dts += dtv;
#pragma unroll
            for (int n = 0; n < 16; n++) {
                float ba = __expf(dtv * Ad[n]);
                h[n] = fmaf(ba, h[n], s_w[r][n]);
            }
        }
    }
    int base = ((b * CHUNKS + c) * D_MODEL + d) * 16;
#pragma unroll
    for (int j = 0; j < 4; j++) {
        f32x4 v = {h[4 * j], h[4 * j + 1], h[4 * j + 2], h[4 * j + 3]};
        *reinterpret_cast<f32x4*>(h_loc + base + 4 * j) = v;
    }
    dtsum[(b * CHUNKS + c) * D_MODEL + d] = dts;
}

// ---------- scan phase 2: combine chunks ----------
__global__ void __launch_bounds__(256) k_scan2(float* __restrict__ h_inout,
                                               const float* __restrict__ dtsum,
                                               const float* __restrict__ aneg) {
    int idx = blockIdx.x * 256 + threadIdx.x;
    int n = idx & 15;
    int d = (idx >> 4) & (D_MODEL - 1);
    int b = idx >> 14;
    float A = aneg[d * 16 + n];
    float H = 0.f;
    int off = (b * CHUNKS) * D_MODEL + d;
    float hl = h_inout[off * 16 + n];
    float ds = dtsum[off];
    for (int c = 0; c < CHUNKS; c++) {
        int off2 = off + D_MODEL;
        float hl_n = 0.f, ds_n = 0.f;
        if (c + 1 < CHUNKS) { hl_n = h_inout[off2 * 16 + n]; ds_n = dtsum[off2]; }
        float P = __expf(ds * A);
        h_inout[off * 16 + n] = H;
        H = fmaf(P, H, hl);
        hl = hl_n; ds = ds_n; off = off2;
    }
}

// ---------- scan phase 3: chunk scan from H_in; emit y (vector staging) ----------
__global__ void __launch_bounds__(256) k_scan3(const unsigned short* __restrict__ dtb,
                                               const unsigned short* __restrict__ xinb,
                                               const float* __restrict__ winp,
                                               const float* __restrict__ bc,
                                               const float* __restrict__ aneg,
                                               const float* __restrict__ dp,
                                               const float* __restrict__ H_in,
                                               float* __restrict__ out) {
    __shared__ unsigned short s_dt[16][256], s_u[16][256];
    __shared__ float s_w[16][16], s_c[16][16];
    int dc = blockIdx.x & 3;
    int c = (blockIdx.x >> 2) & (CHUNKS - 1);
    int b = blockIdx.x >> 8;
    int tid = threadIdx.x;
    int d = dc * 256 + tid;
    float Ad[16];
    const float4* ar = reinterpret_cast<const float4*>(aneg + d * 16);
#pragma unroll
    for (int j = 0; j < 4; j++) {
        float4 a4 = ar[j];
        Ad[4 * j + 0] = a4.x; Ad[4 * j + 1] = a4.y;
        Ad[4 * j + 2] = a4.z; Ad[4 * j + 3] = a4.w;
    }
    float Dpd = dp[d];
    float h[16];
    int base = ((b * CHUNKS + c) * D_MODEL + d) * 16;
#pragma unroll
    for (int j = 0; j < 4; j++) {
        f32x4 v = *reinterpret_cast<const f32x4*>(H_in + base + 4 * j);
        h[4 * j] = v[0]; h[4 * j + 1] = v[1]; h[4 * j + 2] = v[2]; h[4 * j + 3] = v[3];
    }

    int r8 = tid >> 5, col8 = (tid & 31) * 8;
    for (int t0 = 0; t0 < CLEN; t0 += 16) {
        __syncthreads();
        int rowbase = b * SEQ + c * CLEN + t0;
        *reinterpret_cast<uint4*>(&s_dt[r8][col8]) =
            *reinterpret_cast<const uint4*>(dtb + (rowbase + r8) * D_MODEL + dc * 256 + col8);
        *reinterpret_cast<uint4*>(&s_dt[8 + r8][col8]) =
            *reinterpret_cast<const uint4*>(dtb + (rowbase + 8 + r8) * D_MODEL + dc * 256 + col8);
        *reinterpret_cast<uint4*>(&s_u[r8][col8]) =
            *reinterpret_cast<const uint4*>(xinb + (rowbase + r8) * D_MODEL + dc * 256 + col8);
        *reinterpret_cast<uint4*>(&s_u[8 + r8][col8]) =
            *reinterpret_cast<const uint4*>(xinb + (rowbase + 8 + r8) * D_MODEL + dc * 256 + col8);
        {
            int r = tid >> 4, n = tid & 15;
            s_w[r][n] = winp[(rowbase + r) * 16 + n];
            s_c[r][n] = bc[(rowbase + r) * 32 + 16 + n];
        }
        __syncthreads();
        for (int r = 0; r < 16; r++) {
            float dtv = bf2f(s_dt[r][tid]), uv = bf2f(s_u[r][tid]);
            float y = Dpd * uv;
#pragma unroll
            for (int n = 0; n < 16; n++) {
                float ba = __expf(dtv * Ad[n]);
                h[n] = fmaf(ba, h[n], s_w[r][n]);
                y = fmaf(h[n], s_c[r][n], y);
            }
            out[(rowbase + r) * D_MODEL + d] = y;
        }
    }
}

extern "C" void kernel_launch(void* const* d_in, const int* in_sizes, int n_in,
                              void* d_out, int out_size, void* d_ws, size_t ws_size,
                              hipStream_t stream) {
    const float* x     = (const float*)d_in[0];
    const float* w_in  = (const float*)d_in[1];
    const float* w_x   = (const float*)d_in[2];
    const float* w_dt  = (const float*)d_in[3];
    const float* b_dt  = (const float*)d_in[4];
    const float* A_log = (const float*)d_in[5];
    const float* Dp    = (const float*)d_in[6];
    float* out = (float*)d_out;

    char* ws = (char*)d_ws;
    // footprint capped below proven-safe 39124992 B
    unsigned short* xb   = (unsigned short*)(ws + 0);          // 8 MB (dead after gemm)
    unsigned short* bt   = (unsigned short*)(ws + 8388608);    // 4 MB (dead after gemm)
    float* Tt            = (float*)(ws + 12845056);            // 256 KB
    float* aneg          = (float*)(ws + 13107200);            // 64 KB
    float* bc            = (float*)(ws + 13172736);            // 512 KB
    float* winp          = (float*)(ws + 13697024);            // 256 KB
    unsigned short* xinb = (unsigned short*)(ws + 13959168);   // 8 MB
    unsigned short* dtb  = (unsigned short*)(ws + 22347776);   // 8 MB bf16 -> ends 30736384
    // prep-phase overlays of dtb region (dead until gemm writes dtb):
    unsigned short* wib  = (unsigned short*)(ws + 22347776);   // 2 MB   bf16 w_in row-major
    unsigned short* wxT  = (unsigned short*)(ws + 24444928);   // 128 KB bf16 w_x[:, :64]^T
    float* Cp            = (float*)(ws + 24707072);            // 1 MB   K-split partials
    // survives gemm (after dtb):
    unsigned short* wxBC = (unsigned short*)(ws + 30736384);   // 64 KB  bf16 w_x[:,64:96]^T
    // scan-phase overlays of dead xb/bt regions:
    float* h_loc         = (float*)(ws + 0);                   // 8 MB  [b][c][d][n]
    float* dtsum         = (float*)(ws + 8388608);             // 512 KB [b][c][d]

    k_setup<<<6592, 256, 0, stream>>>(x, w_in, w_x, A_log, xb, wib, bt, wxT, wxBC, aneg);
    k_prepgemm<<<32, 256, 0, stream>>>(wxT, wib, Cp);
    k_prepreduce<<<256, 256, 0, stream>>>(Cp, Tt);
    k_prep2<<<128, 256, 0, stream>>>(w_dt, Tt, bt);
    k_gemm_big<<<512, 256, 0, stream>>>(xb, bt, b_dt, xinb, dtb);
    k_winp<<<2048, 256, 0, stream>>>(dtb, xinb, aneg, wxBC, bc, winp);
    k_scan1<<<BATCH * CHUNKS * 4, 256, 0, stream>>>(dtb, winp, aneg, h_loc, dtsum);
    k_scan2<<<128, 256, 0, stream>>>(h_loc, dtsum, aneg);
    k_scan3<<<BATCH * CHUNKS * 4, 256, 0, stream>>>(dtb, xinb, winp, bc, aneg, Dp, h_loc, out);
}

// Round 10
// 188.550 us; speedup vs baseline: 1.2365x; 1.2365x over previous
//
#include <hip/hip_runtime.h>
#include <hip/hip_bf16.h>

#define D_MODEL 1024
#define D_STATE 16
#define DT_RANK 64
#define SEQ 2048
#define BATCH 2
#define M_TOTAL 4096
#define CHUNKS 64
#define CLEN 32

typedef __bf16 bf16x8 __attribute__((ext_vector_type(8)));
typedef float f32x4 __attribute__((ext_vector_type(4)));

__device__ __forceinline__ unsigned short f2bf(float f) {
    union { float f; unsigned int u; } v; v.f = f;
    unsigned int r = v.u + 0x7FFFu + ((v.u >> 16) & 1u);
    return (unsigned short)(r >> 16);
}
__device__ __forceinline__ float bf2f(unsigned short u) {
    union { unsigned int i; float f; } v; v.i = ((unsigned int)u) << 16; return v.f;
}
__device__ __forceinline__ void gload16(const void* g, void* l) {
    __builtin_amdgcn_global_load_lds(
        (const __attribute__((address_space(1))) unsigned int*)g,
        (__attribute__((address_space(3))) unsigned int*)l, 16, 0, 0);
}

// ---------- fused setup ----------
__global__ void __launch_bounds__(256) k_setup(const float* __restrict__ x,
                                               const float* __restrict__ win,
                                               const float* __restrict__ wx,
                                               const float* __restrict__ alog,
                                               unsigned short* __restrict__ xb,
                                               unsigned short* __restrict__ wib,
                                               unsigned short* __restrict__ bt,
                                               unsigned short* __restrict__ wxT,
                                               unsigned short* __restrict__ wxBC,
                                               float* __restrict__ aneg) {
    __shared__ float tile[32][33];
    int blk = blockIdx.x;
    int t = threadIdx.x;
    if (blk < 4096) {
        int i = blk * 256 + t;
        float4 v = reinterpret_cast<const float4*>(x)[i];
        ushort4 o;
        o.x = f2bf(v.x); o.y = f2bf(v.y); o.z = f2bf(v.z); o.w = f2bf(v.w);
        reinterpret_cast<ushort4*>(xb)[i] = o;
    } else if (blk < 5120) {
        int i = (blk - 4096) * 256 + t;
        float4 v = reinterpret_cast<const float4*>(win)[i];
        ushort4 o;
        o.x = f2bf(v.x); o.y = f2bf(v.y); o.z = f2bf(v.z); o.w = f2bf(v.w);
        reinterpret_cast<ushort4*>(wib)[i] = o;
    } else if (blk < 6144) {
        int blk2 = blk - 5120;
        int bx = blk2 & 31, by = blk2 >> 5;
        int tx = t & 31, ty = t >> 5;
        int xc = bx * 32 + tx;
#pragma unroll
        for (int j = 0; j < 4; j++)
            tile[ty + 8 * j][tx] = win[(by * 32 + ty + 8 * j) * D_MODEL + xc];
        __syncthreads();
        int x2 = by * 32 + tx;
#pragma unroll
        for (int j = 0; j < 4; j++)
            bt[(bx * 32 + ty + 8 * j) * D_MODEL + x2] = f2bf(tile[tx][ty + 8 * j]);
    } else if (blk < 6400) {  // wxT rows 0..63 (dt_low cols of w_x)
        int idx = (blk - 6144) * 256 + t;
        int e = idx & 1023, p = idx >> 10;
        wxT[p * D_MODEL + e] = f2bf(wx[e * 96 + p]);
    } else if (blk < 6528) {  // wxBC[p][e] = w_x[e][64+p], p<32
        int idx = (blk - 6400) * 256 + t;
        int e = idx & 1023, p = idx >> 10;
        wxBC[p * D_MODEL + e] = f2bf(wx[e * 96 + 64 + p]);
    } else {
        int i = (blk - 6528) * 256 + t;
        if (i < D_MODEL * D_STATE) aneg[i] = -expf(alog[i]);
    }
}

// ---------- prep GEMM: Cp[ks*64+p][d] partials of (w_x[:, :64]^T @ w_in) ----------
__global__ void __launch_bounds__(256) k_prepgemm(const unsigned short* __restrict__ wxT,
                                                  const unsigned short* __restrict__ wib,
                                                  float* __restrict__ Cp) {
    __shared__ unsigned short sA[2][64 * 32];
    __shared__ unsigned short sB[2][128 * 32];
    int bid = blockIdx.x;  // 32 = 8 n x 4 ksplit
    int n0 = (bid & 7) * 128;
    int ks = bid >> 3;
    int kbase = ks * 256;
    int t = threadIdx.x;
    int lane = t & 63;
    int w = t >> 6;
    int c = lane & 15, q = lane >> 4;

    const unsigned short* ga = wxT + (t >> 2) * D_MODEL + (t & 3) * 8 + kbase;
    const unsigned short* gb = wib + (n0 + (t >> 2)) * D_MODEL + (t & 3) * 8 + kbase;

    f32x4 acc[4][2] = {};
    {
        char* la = (char*)&sA[0][0] + w * 1024;
        char* lb = (char*)&sB[0][0] + w * 1024;
        gload16(ga, la);
        gload16(gb, lb);
        gload16(gb + 64 * D_MODEL, lb + 4096);
    }
    int cur = 0;
    for (int it = 0; it < 8; it++) {
        __syncthreads();
        if (it + 1 < 8) {
            int kn = (it + 1) * 32;
            char* la = (char*)&sA[cur ^ 1][0] + w * 1024;
            char* lb = (char*)&sB[cur ^ 1][0] + w * 1024;
            gload16(ga + kn, la);
            gload16(gb + kn, lb);
            gload16(gb + 64 * D_MODEL + kn, lb + 4096);
        }
        bf16x8 af[4], bfr[2];
#pragma unroll
        for (int i = 0; i < 4; i++)
            af[i] = *reinterpret_cast<const bf16x8*>(&sA[cur][(i * 16 + c) * 32 + q * 8]);
#pragma unroll
        for (int j = 0; j < 2; j++)
            bfr[j] = *reinterpret_cast<const bf16x8*>(&sB[cur][(w * 32 + j * 16 + c) * 32 + q * 8]);
#pragma unroll
        for (int i = 0; i < 4; i++)
#pragma unroll
            for (int j = 0; j < 2; j++)
                acc[i][j] = __builtin_amdgcn_mfma_f32_16x16x32_bf16(af[i], bfr[j], acc[i][j], 0, 0, 0);
        cur ^= 1;
    }
#pragma unroll
    for (int i = 0; i < 4; i++) {
        int p = i * 16 + q * 4;
#pragma unroll
        for (int j = 0; j < 2; j++) {
            int d = n0 + w * 32 + j * 16 + c;
#pragma unroll
            for (int r = 0; r < 4; r++)
                Cp[(ks * 64 + p + r) * D_MODEL + d] = acc[i][j][r];
        }
    }
}

// ---------- prep reduce: Tt[p][d] = sum_ks Cp ----------
__global__ void __launch_bounds__(256) k_prepreduce(const float* __restrict__ Cp,
                                                    float* __restrict__ Tt) {
    int idx = blockIdx.x * 256 + threadIdx.x;  // 64*1024
    int d = idx & 1023;
    int p = idx >> 10;
    Tt[p * D_MODEL + d] = Cp[p * D_MODEL + d] + Cp[(64 + p) * D_MODEL + d] +
                          Cp[(128 + p) * D_MODEL + d] + Cp[(192 + p) * D_MODEL + d];
}

// ---------- prep2: bt rows 1024..2047 = (Tt^T @ w_dt)^T bf16 ----------
__global__ void __launch_bounds__(256) k_prep2(const float* __restrict__ wdt,
                                               const float* __restrict__ Tt,
                                               unsigned short* __restrict__ bt) {
    __shared__ float sw[DT_RANK][8];
    int m0 = blockIdx.x * 8;
    int tid = threadIdx.x;
    for (int s = tid; s < DT_RANK * 8; s += 256) {
        int r = s >> 3, rr = s & 7;
        sw[r][rr] = wdt[r * D_MODEL + m0 + rr];
    }
    __syncthreads();
    float acc[8][4] = {};
    for (int r = 0; r < DT_RANK; r++) {
        float tv0 = Tt[r * D_MODEL + tid];
        float tv1 = Tt[r * D_MODEL + tid + 256];
        float tv2 = Tt[r * D_MODEL + tid + 512];
        float tv3 = Tt[r * D_MODEL + tid + 768];
#pragma unroll
        for (int rr = 0; rr < 8; rr++) {
            float wv = sw[r][rr];
            acc[rr][0] = fmaf(wv, tv0, acc[rr][0]);
            acc[rr][1] = fmaf(wv, tv1, acc[rr][1]);
            acc[rr][2] = fmaf(wv, tv2, acc[rr][2]);
            acc[rr][3] = fmaf(wv, tv3, acc[rr][3]);
        }
    }
#pragma unroll
    for (int rr = 0; rr < 8; rr++)
#pragma unroll
        for (int i = 0; i < 4; i++)
            bt[(D_MODEL + m0 + rr) * D_MODEL + tid + i * 256] = f2bf(acc[rr][i]);
}

// ---------- big GEMM: 128x128 tile, BK=64, dbuf, XOR-swizzled LDS, grid 512 (2/CU) ----------
__global__ void __launch_bounds__(256) k_gemm_big(const unsigned short* __restrict__ xb,
                                                  const unsigned short* __restrict__ bt,
                                                  const float* __restrict__ bdt,
                                                  unsigned short* __restrict__ xinb,
                                                  unsigned short* __restrict__ dtb) {
    __shared__ unsigned short sA[2][128 * 64];
    __shared__ unsigned short sB[2][128 * 64];
    int bid = blockIdx.x;
    int m0 = (bid & 31) * 128;
    int nt = bid >> 5;  // 0..15
    int n0 = nt * 128;
    int t = threadIdx.x;
    int lane = t & 63;
    int w = t >> 6;
    int wm = (w >> 1) * 64, wn = (w & 1) * 64;
    int c = lane & 15, q = lane >> 4;

    const unsigned short* gA[4];
    const unsigned short* gB[4];
#pragma unroll
    for (int L = 0; L < 4; L++) {
        int s = L * 256 + t;
        int row = s >> 3, ch = (s & 7) ^ (row & 7);
        gA[L] = xb + (m0 + row) * D_MODEL + ch * 8;
        gB[L] = bt + (n0 + row) * D_MODEL + ch * 8;
    }

    f32x4 acc[4][4] = {};
    {
        char* la = (char*)&sA[0][0] + w * 1024;
        char* lb = (char*)&sB[0][0] + w * 1024;
#pragma unroll
        for (int L = 0; L < 4; L++) {
            gload16(gA[L], la + L * 4096);
            gload16(gB[L], lb + L * 4096);
        }
    }
    int cur = 0;
    for (int it = 0; it < 16; it++) {
        __syncthreads();
        if (it + 1 < 16) {
            int kn = (it + 1) * 64;
            char* la = (char*)&sA[cur ^ 1][0] + w * 1024;
            char* lb = (char*)&sB[cur ^ 1][0] + w * 1024;
#pragma unroll
            for (int L = 0; L < 4; L++) {
                gload16(gA[L] + kn, la + L * 4096);
                gload16(gB[L] + kn, lb + L * 4096);
            }
        }
#pragma unroll
        for (int kk = 0; kk < 2; kk++) {
            int perm = (((kk << 2) | q) ^ (c & 7)) << 3;
            bf16x8 af[4], bfr[4];
#pragma unroll
            for (int i = 0; i < 4; i++)
                af[i] = *reinterpret_cast<const bf16x8*>(&sA[cur][(wm + i * 16 + c) * 64 + perm]);
#pragma unroll
            for (int j = 0; j < 4; j++)
                bfr[j] = *reinterpret_cast<const bf16x8*>(&sB[cur][(wn + j * 16 + c) * 64 + perm]);
#pragma unroll
            for (int i = 0; i < 4; i++)
#pragma unroll
                for (int j = 0; j < 4; j++)
                    acc[i][j] = __builtin_amdgcn_mfma_f32_16x16x32_bf16(af[i], bfr[j], acc[i][j], 0, 0, 0);
        }
        cur ^= 1;
    }

    if (nt < 8) {
#pragma unroll
        for (int i = 0; i < 4; i++) {
            int row = m0 + wm + i * 16 + q * 4;
#pragma unroll
            for (int j = 0; j < 4; j++) {
                int col = n0 + wn + j * 16 + c;
#pragma unroll
                for (int r = 0; r < 4; r++)
                    xinb[(row + r) * D_MODEL + col] = f2bf(acc[i][j][r]);
            }
        }
    } else {
#pragma unroll
        for (int i = 0; i < 4; i++) {
            int row = m0 + wm + i * 16 + q * 4;
#pragma unroll
            for (int j = 0; j < 4; j++) {
                int dcol = n0 + wn + j * 16 + c - D_MODEL;
                float bv = bdt[dcol];
#pragma unroll
                for (int r = 0; r < 4; r++) {
                    float xv = acc[i][j][r] + bv;
                    float sp = fmaxf(xv, 0.f) + __logf(1.f + __expf(-fabsf(xv)));
                    dtb[(row + r) * D_MODEL + dcol] = f2bf(sp * 0.099f + 0.001f);
                }
            }
        }
    }
}

// ---------- BC GEMM: bcp[ks][m][p] partials of x_in @ w_x[:,64:96]; direct-global MFMA ----------
__global__ void __launch_bounds__(256) k_bc(const unsigned short* __restrict__ xinb,
                                            const unsigned short* __restrict__ wxBC,
                                            float* __restrict__ bcp) {
    int bid = blockIdx.x;  // 128 = 32 mtiles x 4 ksplit
    int m0 = (bid & 31) * 128;
    int ks = bid >> 5;
    int kbase = ks * 256;
    int t = threadIdx.x;
    int lane = t & 63, w = t >> 6;
    int c = lane & 15, q = lane >> 4;
    int mw = m0 + w * 32;
    f32x4 acc[2][2] = {};
    const unsigned short* pa0 = xinb + (mw + c) * D_MODEL + kbase + q * 8;
    const unsigned short* pa1 = xinb + (mw + 16 + c) * D_MODEL + kbase + q * 8;
    const unsigned short* pb0 = wxBC + c * D_MODEL + kbase + q * 8;
    const unsigned short* pb1 = wxBC + (16 + c) * D_MODEL + kbase + q * 8;
#pragma unroll
    for (int k0 = 0; k0 < 256; k0 += 32) {
        bf16x8 a0 = *reinterpret_cast<const bf16x8*>(pa0 + k0);
        bf16x8 a1 = *reinterpret_cast<const bf16x8*>(pa1 + k0);
        bf16x8 b0 = *reinterpret_cast<const bf16x8*>(pb0 + k0);
        bf16x8 b1 = *reinterpret_cast<const bf16x8*>(pb1 + k0);
        acc[0][0] = __builtin_amdgcn_mfma_f32_16x16x32_bf16(a0, b0, acc[0][0], 0, 0, 0);
        acc[0][1] = __builtin_amdgcn_mfma_f32_16x16x32_bf16(a0, b1, acc[0][1], 0, 0, 0);
        acc[1][0] = __builtin_amdgcn_mfma_f32_16x16x32_bf16(a1, b0, acc[1][0], 0, 0, 0);
        acc[1][1] = __builtin_amdgcn_mfma_f32_16x16x32_bf16(a1, b1, acc[1][1], 0, 0, 0);
    }
    // C/D: col = c, row = q*4 + r
#pragma unroll
    for (int i = 0; i < 2; i++) {
        int row = mw + i * 16 + q * 4;
#pragma unroll
        for (int j = 0; j < 2; j++) {
            int p = j * 16 + c;
#pragma unroll
            for (int r = 0; r < 4; r++)
                bcp[(ks * M_TOTAL + row + r) * 32 + p] = acc[i][j][r];
        }
    }
}

// ---------- winp: coalesced reduce + bcp finalize ----------
__global__ void __launch_bounds__(256) k_winp(const unsigned short* __restrict__ dtb,
                                              const unsigned short* __restrict__ xinb,
                                              const float* __restrict__ aneg,
                                              const float* __restrict__ bcp,
                                              float* __restrict__ bc,
                                              float* __restrict__ winp) {
    __shared__ float r0[16][17], r1[16][17];
    __shared__ float sb[2][32];
    int m = blockIdx.x * 2;
    int tid = threadIdx.x;
    int n = tid & 15, strip = tid >> 4;
    float a0 = 0.f, a1 = 0.f;
    int d0 = strip * 64;
    for (int dd = 0; dd < 64; dd += 4) {
        int d = d0 + dd;
        ushort4 t0 = *reinterpret_cast<const ushort4*>(dtb + m * D_MODEL + d);
        ushort4 u0 = *reinterpret_cast<const ushort4*>(xinb + m * D_MODEL + d);
        ushort4 t1 = *reinterpret_cast<const ushort4*>(dtb + (m + 1) * D_MODEL + d);
        ushort4 u1 = *reinterpret_cast<const ushort4*>(xinb + (m + 1) * D_MODEL + d);
        float av0 = aneg[(d + 0) * 16 + n];
        float av1 = aneg[(d + 1) * 16 + n];
        float av2 = aneg[(d + 2) * 16 + n];
        float av3 = aneg[(d + 3) * 16 + n];
        a0 = fmaf(bf2f(t0.x) * bf2f(u0.x), av0, a0);
        a0 = fmaf(bf2f(t0.y) * bf2f(u0.y), av1, a0);
        a0 = fmaf(bf2f(t0.z) * bf2f(u0.z), av2, a0);
        a0 = fmaf(bf2f(t0.w) * bf2f(u0.w), av3, a0);
        a1 = fmaf(bf2f(t1.x) * bf2f(u1.x), av0, a1);
        a1 = fmaf(bf2f(t1.y) * bf2f(u1.y), av1, a1);
        a1 = fmaf(bf2f(t1.z) * bf2f(u1.z), av2, a1);
        a1 = fmaf(bf2f(t1.w) * bf2f(u1.w), av3, a1);
    }
    r0[strip][n] = a0; r1[strip][n] = a1;
    if (tid < 64) {  // finalize bc for rows m, m+1
        int row = m + (tid >> 5), p = tid & 31;
        float s = bcp[row * 32 + p] + bcp[(M_TOTAL + row) * 32 + p] +
                  bcp[(2 * M_TOTAL + row) * 32 + p] + bcp[(3 * M_TOTAL + row) * 32 + p];
        bc[row * 32 + p] = s;
        sb[tid >> 5][p] = s;
    }
    __syncthreads();
    for (int s = 8; s > 0; s >>= 1) {
        if (strip < s) {
            r0[strip][n] += r0[strip + s][n];
            r1[strip][n] += r1[strip + s][n];
        }
        __syncthreads();
    }
    if (tid < 16) winp[m * 16 + n] = sb[0][n] * r0[0][n];
    else if (tid < 32) winp[(m + 1) * 16 + n] = sb[1][n] * r1[0][n];
}

// ---------- scan phase 1: chunk-local scan -> h_loc, dtsum (vector staging) ----------
__global__ void __launch_bounds__(256) k_scan1(const unsigned short* __restrict__ dtb,
                                               const float* __restrict__ winp,
                                               const float* __restrict__ aneg,
                                               float* __restrict__ h_loc,
                                               float* __restrict__ dtsum) {
    __shared__ unsigned short s_dt[16][256];
    __shared__ float s_w[16][16];
    int dc = blockIdx.x & 3;
    int c = (blockIdx.x >> 2) & (CHUNKS - 1);
    int b = blockIdx.x >> 8;
    int tid = threadIdx.x;
    int d = dc * 256 + tid;
    float Ad[16];
    const float4* ar = reinterpret_cast<const float4*>(aneg + d * 16);
#pragma unroll
    for (int j = 0; j < 4; j++) {
        float4 a4 = ar[j];
        Ad[4 * j + 0] = a4.x; Ad[4 * j + 1] = a4.y;
        Ad[4 * j + 2] = a4.z; Ad[4 * j + 3] = a4.w;
    }
    float h[16];
#pragma unroll
    for (int n = 0; n < 16; n++) h[n] = 0.f;
    float dts = 0.f;

    int r8 = tid >> 5, col8 = (tid & 31) * 8;
    for (int t0 = 0; t0 < CLEN; t0 += 16) {
        __syncthreads();
        int rowbase = b * SEQ + c * CLEN + t0;
        *reinterpret_cast<uint4*>(&s_dt[r8][col8]) =
            *reinterpret_cast<const uint4*>(dtb + (rowbase + r8) * D_MODEL + dc * 256 + col8);
        *reinterpret_cast<uint4*>(&s_dt[8 + r8][col8]) =
            *reinterpret_cast<const uint4*>(dtb + (rowbase + 8 + r8) * D_MODEL + dc * 256 + col8);
        {
            int r = tid >> 4, n = tid & 15;
            s_w[r][n] = winp[(rowbase + r) * 16 + n];
        }
        __syncthreads();
        for (int r = 0; r < 16; r++) {
            float dtv = bf2f(s_dt[r][tid]);
            dts += dtv;
#pragma unroll
            for (int n = 0; n < 16; n++) {
                float ba = __expf(dtv * Ad[n]);
                h[n] = fmaf(ba, h[n], s_w[r][n]);
            }
        }
    }
    int base = ((b * CHUNKS + c) * D_MODEL + d) * 16;
#pragma unroll
    for (int j = 0; j < 4; j++) {
        f32x4 v = {h[4 * j], h[4 * j + 1], h[4 * j + 2], h[4 * j + 3]};
        *reinterpret_cast<f32x4*>(h_loc + base + 4 * j) = v;
    }
    dtsum[(b * CHUNKS + c) * D_MODEL + d] = dts;
}

// ---------- scan phase 2: combine chunks ----------
__global__ void __launch_bounds__(256) k_scan2(float* __restrict__ h_inout,
                                               const float* __restrict__ dtsum,
                                               const float* __restrict__ aneg) {
    int idx = blockIdx.x * 256 + threadIdx.x;
    int n = idx & 15;
    int d = (idx >> 4) & (D_MODEL - 1);
    int b = idx >> 14;
    float A = aneg[d * 16 + n];
    float H = 0.f;
    int off = (b * CHUNKS) * D_MODEL + d;
    float hl = h_inout[off * 16 + n];
    float ds = dtsum[off];
    for (int c = 0; c < CHUNKS; c++) {
        int off2 = off + D_MODEL;
        float hl_n = 0.f, ds_n = 0.f;
        if (c + 1 < CHUNKS) { hl_n = h_inout[off2 * 16 + n]; ds_n = dtsum[off2]; }
        float P = __expf(ds * A);
        h_inout[off * 16 + n] = H;
        H = fmaf(P, H, hl);
        hl = hl_n; ds = ds_n; off = off2;
    }
}

// ---------- scan phase 3: chunk scan from H_in; emit y (vector staging) ----------
__global__ void __launch_bounds__(256) k_scan3(const unsigned short* __restrict__ dtb,
                                               const unsigned short* __restrict__ xinb,
                                               const float* __restrict__ winp,
                                               const float* __restrict__ bc,
                                               const float* __restrict__ aneg,
                                               const float* __restrict__ dp,
                                               const float* __restrict__ H_in,
                                               float* __restrict__ out) {
    __shared__ unsigned short s_dt[16][256], s_u[16][256];
    __shared__ float s_w[16][16], s_c[16][16];
    int dc = blockIdx.x & 3;
    int c = (blockIdx.x >> 2) & (CHUNKS - 1);
    int b = blockIdx.x >> 8;
    int tid = threadIdx.x;
    int d = dc * 256 + tid;
    float Ad[16];
    const float4* ar = reinterpret_cast<const float4*>(aneg + d * 16);
#pragma unroll
    for (int j = 0; j < 4; j++) {
        float4 a4 = ar[j];
        Ad[4 * j + 0] = a4.x; Ad[4 * j + 1] = a4.y;
        Ad[4 * j + 2] = a4.z; Ad[4 * j + 3] = a4.w;
    }
    float Dpd = dp[d];
    float h[16];
    int base = ((b * CHUNKS + c) * D_MODEL + d) * 16;
#pragma unroll
    for (int j = 0; j < 4; j++) {
        f32x4 v = *reinterpret_cast<const f32x4*>(H_in + base + 4 * j);
        h[4 * j] = v[0]; h[4 * j + 1] = v[1]; h[4 * j + 2] = v[2]; h[4 * j + 3] = v[3];
    }

    int r8 = tid >> 5, col8 = (tid & 31) * 8;
    for (int t0 = 0; t0 < CLEN; t0 += 16) {
        __syncthreads();
        int rowbase = b * SEQ + c * CLEN + t0;
        *reinterpret_cast<uint4*>(&s_dt[r8][col8]) =
            *reinterpret_cast<const uint4*>(dtb + (rowbase + r8) * D_MODEL + dc * 256 + col8);
        *reinterpret_cast<uint4*>(&s_dt[8 + r8][col8]) =
            *reinterpret_cast<const uint4*>(dtb + (rowbase + 8 + r8) * D_MODEL + dc * 256 + col8);
        *reinterpret_cast<uint4*>(&s_u[r8][col8]) =
            *reinterpret_cast<const uint4*>(xinb + (rowbase + r8) * D_MODEL + dc * 256 + col8);
        *reinterpret_cast<uint4*>(&s_u[8 + r8][col8]) =
            *reinterpret_cast<const uint4*>(xinb + (rowbase + 8 + r8) * D_MODEL + dc * 256 + col8);
        {
            int r = tid >> 4, n = tid & 15;
            s_w[r][n] = winp[(rowbase + r) * 16 + n];
            s_c[r][n] = bc[(rowbase + r) * 32 + 16 + n];
        }
        __syncthreads();
        for (int r = 0; r < 16; r++) {
            float dtv = bf2f(s_dt[r][tid]), uv = bf2f(s_u[r][tid]);
            float y = Dpd * uv;
#pragma unroll
            for (int n = 0; n < 16; n++) {
                float ba = __expf(dtv * Ad[n]);
                h[n] = fmaf(ba, h[n], s_w[r][n]);
                y = fmaf(h[n], s_c[r][n], y);
            }
            out[(rowbase + r) * D_MODEL + d] = y;
        }
    }
}

extern "C" void kernel_launch(void* const* d_in, const int* in_sizes, int n_in,
                              void* d_out, int out_size, void* d_ws, size_t ws_size,
                              hipStream_t stream) {
    const float* x     = (const float*)d_in[0];
    const float* w_in  = (const float*)d_in[1];
    const float* w_x   = (const float*)d_in[2];
    const float* w_dt  = (const float*)d_in[3];
    const float* b_dt  = (const float*)d_in[4];
    const float* A_log = (const float*)d_in[5];
    const float* Dp    = (const float*)d_in[6];
    float* out = (float*)d_out;

    char* ws = (char*)d_ws;
    // footprint capped below proven-safe 39124992 B
    unsigned short* xb   = (unsigned short*)(ws + 0);          // 8 MB (dead after gemm)
    unsigned short* bt   = (unsigned short*)(ws + 8388608);    // 4 MB (dead after gemm)
    float* Tt            = (float*)(ws + 12845056);            // 256 KB
    float* aneg          = (float*)(ws + 13107200);            // 64 KB
    float* bc            = (float*)(ws + 13172736);            // 512 KB
    float* winp          = (float*)(ws + 13697024);            // 256 KB
    unsigned short* xinb = (unsigned short*)(ws + 13959168);   // 8 MB
    unsigned short* dtb  = (unsigned short*)(ws + 22347776);   // 8 MB bf16 -> ends 30736384
    // prep-phase overlays of dtb region (dead until gemm writes dtb):
    unsigned short* wib  = (unsigned short*)(ws + 22347776);   // 2 MB   bf16 w_in row-major
    unsigned short* wxT  = (unsigned short*)(ws + 24444928);   // 128 KB bf16 w_x[:, :64]^T
    float* Cp            = (float*)(ws + 24707072);            // 1 MB   K-split partials
    // survive gemm (after dtb):
    unsigned short* wxBC = (unsigned short*)(ws + 30736384);   // 64 KB  bf16 w_x[:,64:96]^T
    float* bcp           = (float*)(ws + 30801920);            // 2 MB   BC K-split partials -> ends 32899072
    // scan-phase overlays of dead xb/bt regions:
    float* h_loc         = (float*)(ws + 0);                   // 8 MB  [b][c][d][n]
    float* dtsum         = (float*)(ws + 8388608);             // 512 KB [b][c][d]

    k_setup<<<6592, 256, 0, stream>>>(x, w_in, w_x, A_log, xb, wib, bt, wxT, wxBC, aneg);
    k_prepgemm<<<32, 256, 0, stream>>>(wxT, wib, Cp);
    k_prepreduce<<<256, 256, 0, stream>>>(Cp, Tt);
    k_prep2<<<128, 256, 0, stream>>>(w_dt, Tt, bt);
    k_gemm_big<<<512, 256, 0, stream>>>(xb, bt, b_dt, xinb, dtb);
    k_bc<<<128, 256, 0, stream>>>(xinb, wxBC, bcp);
    k_winp<<<2048, 256, 0, stream>>>(dtb, xinb, aneg, bcp, bc, winp);
    k_scan1<<<BATCH * CHUNKS * 4, 256, 0, stream>>>(dtb, winp, aneg, h_loc, dtsum);
    k_scan2<<<128, 256, 0, stream>>>(h_loc, dtsum, aneg);
    k_scan3<<<BATCH * CHUNKS * 4, 256, 0, stream>>>(dtb, xinb, winp, bc, aneg, Dp, h_loc, out);
}

// Round 11
// 176.593 us; speedup vs baseline: 1.3202x; 1.0677x over previous
//
#include <hip/hip_runtime.h>
#include <hip/hip_bf16.h>

#define D_MODEL 1024
#define D_STATE 16
#define DT_RANK 64
#define SEQ 2048
#define BATCH 2
#define M_TOTAL 4096
#define CHUNKS 64
#define CLEN 32

typedef __bf16 bf16x8 __attribute__((ext_vector_type(8)));
typedef float f32x4 __attribute__((ext_vector_type(4)));

__device__ __forceinline__ unsigned short f2bf(float f) {
    union { float f; unsigned int u; } v; v.f = f;
    unsigned int r = v.u + 0x7FFFu + ((v.u >> 16) & 1u);
    return (unsigned short)(r >> 16);
}
__device__ __forceinline__ float bf2f(unsigned short u) {
    union { unsigned int i; float f; } v; v.i = ((unsigned int)u) << 16; return v.f;
}
__device__ __forceinline__ void gload16(const void* g, void* l) {
    __builtin_amdgcn_global_load_lds(
        (const __attribute__((address_space(1))) unsigned int*)g,
        (__attribute__((address_space(3))) unsigned int*)l, 16, 0, 0);
}

// ---------- fused setup ----------
__global__ void __launch_bounds__(256) k_setup(const float* __restrict__ x,
                                               const float* __restrict__ win,
                                               const float* __restrict__ wx,
                                               const float* __restrict__ alog,
                                               unsigned short* __restrict__ xb,
                                               unsigned short* __restrict__ wib,
                                               unsigned short* __restrict__ bt,
                                               unsigned short* __restrict__ wxT,
                                               unsigned short* __restrict__ wxBC,
                                               float* __restrict__ aneg,
                                               unsigned short* __restrict__ anegT) {
    __shared__ float tile[32][33];
    int blk = blockIdx.x;
    int t = threadIdx.x;
    if (blk < 4096) {
        int i = blk * 256 + t;
        float4 v = reinterpret_cast<const float4*>(x)[i];
        ushort4 o;
        o.x = f2bf(v.x); o.y = f2bf(v.y); o.z = f2bf(v.z); o.w = f2bf(v.w);
        reinterpret_cast<ushort4*>(xb)[i] = o;
    } else if (blk < 5120) {
        int i = (blk - 4096) * 256 + t;
        float4 v = reinterpret_cast<const float4*>(win)[i];
        ushort4 o;
        o.x = f2bf(v.x); o.y = f2bf(v.y); o.z = f2bf(v.z); o.w = f2bf(v.w);
        reinterpret_cast<ushort4*>(wib)[i] = o;
    } else if (blk < 6144) {
        int blk2 = blk - 5120;
        int bx = blk2 & 31, by = blk2 >> 5;
        int tx = t & 31, ty = t >> 5;
        int xc = bx * 32 + tx;
#pragma unroll
        for (int j = 0; j < 4; j++)
            tile[ty + 8 * j][tx] = win[(by * 32 + ty + 8 * j) * D_MODEL + xc];
        __syncthreads();
        int x2 = by * 32 + tx;
#pragma unroll
        for (int j = 0; j < 4; j++)
            bt[(bx * 32 + ty + 8 * j) * D_MODEL + x2] = f2bf(tile[tx][ty + 8 * j]);
    } else if (blk < 6400) {  // wxT rows 0..63 (dt_low cols of w_x)
        int idx = (blk - 6144) * 256 + t;
        int e = idx & 1023, p = idx >> 10;
        wxT[p * D_MODEL + e] = f2bf(wx[e * 96 + p]);
    } else if (blk < 6528) {  // wxBC[p][e] = w_x[e][64+p], p<32
        int idx = (blk - 6400) * 256 + t;
        int e = idx & 1023, p = idx >> 10;
        wxBC[p * D_MODEL + e] = f2bf(wx[e * 96 + 64 + p]);
    } else {  // aneg (fp32, [d][n]) + anegT (bf16, [n][d])
        int i = (blk - 6528) * 256 + t;  // 64 blocks -> 16384 exact
        float v = -expf(alog[i]);
        aneg[i] = v;
        anegT[(i & 15) * D_MODEL + (i >> 4)] = f2bf(v);
    }
}

// ---------- prep GEMM: Cp[ks*64+p][d] partials of (w_x[:, :64]^T @ w_in) ----------
__global__ void __launch_bounds__(256) k_prepgemm(const unsigned short* __restrict__ wxT,
                                                  const unsigned short* __restrict__ wib,
                                                  float* __restrict__ Cp) {
    __shared__ unsigned short sA[2][64 * 32];
    __shared__ unsigned short sB[2][128 * 32];
    int bid = blockIdx.x;  // 32 = 8 n x 4 ksplit
    int n0 = (bid & 7) * 128;
    int ks = bid >> 3;
    int kbase = ks * 256;
    int t = threadIdx.x;
    int lane = t & 63;
    int w = t >> 6;
    int c = lane & 15, q = lane >> 4;

    const unsigned short* ga = wxT + (t >> 2) * D_MODEL + (t & 3) * 8 + kbase;
    const unsigned short* gb = wib + (n0 + (t >> 2)) * D_MODEL + (t & 3) * 8 + kbase;

    f32x4 acc[4][2] = {};
    {
        char* la = (char*)&sA[0][0] + w * 1024;
        char* lb = (char*)&sB[0][0] + w * 1024;
        gload16(ga, la);
        gload16(gb, lb);
        gload16(gb + 64 * D_MODEL, lb + 4096);
    }
    int cur = 0;
    for (int it = 0; it < 8; it++) {
        __syncthreads();
        if (it + 1 < 8) {
            int kn = (it + 1) * 32;
            char* la = (char*)&sA[cur ^ 1][0] + w * 1024;
            char* lb = (char*)&sB[cur ^ 1][0] + w * 1024;
            gload16(ga + kn, la);
            gload16(gb + kn, lb);
            gload16(gb + 64 * D_MODEL + kn, lb + 4096);
        }
        bf16x8 af[4], bfr[2];
#pragma unroll
        for (int i = 0; i < 4; i++)
            af[i] = *reinterpret_cast<const bf16x8*>(&sA[cur][(i * 16 + c) * 32 + q * 8]);
#pragma unroll
        for (int j = 0; j < 2; j++)
            bfr[j] = *reinterpret_cast<const bf16x8*>(&sB[cur][(w * 32 + j * 16 + c) * 32 + q * 8]);
#pragma unroll
        for (int i = 0; i < 4; i++)
#pragma unroll
            for (int j = 0; j < 2; j++)
                acc[i][j] = __builtin_amdgcn_mfma_f32_16x16x32_bf16(af[i], bfr[j], acc[i][j], 0, 0, 0);
        cur ^= 1;
    }
#pragma unroll
    for (int i = 0; i < 4; i++) {
        int p = i * 16 + q * 4;
#pragma unroll
        for (int j = 0; j < 2; j++) {
            int d = n0 + w * 32 + j * 16 + c;
#pragma unroll
            for (int r = 0; r < 4; r++)
                Cp[(ks * 64 + p + r) * D_MODEL + d] = acc[i][j][r];
        }
    }
}

// ---------- prep reduce: Tt[p][d] = sum_ks Cp ----------
__global__ void __launch_bounds__(256) k_prepreduce(const float* __restrict__ Cp,
                                                    float* __restrict__ Tt) {
    int idx = blockIdx.x * 256 + threadIdx.x;  // 64*1024
    int d = idx & 1023;
    int p = idx >> 10;
    Tt[p * D_MODEL + d] = Cp[p * D_MODEL + d] + Cp[(64 + p) * D_MODEL + d] +
                          Cp[(128 + p) * D_MODEL + d] + Cp[(192 + p) * D_MODEL + d];
}

// ---------- prep2: bt rows 1024..2047 = (Tt^T @ w_dt)^T bf16 ----------
__global__ void __launch_bounds__(256) k_prep2(const float* __restrict__ wdt,
                                               const float* __restrict__ Tt,
                                               unsigned short* __restrict__ bt) {
    __shared__ float sw[DT_RANK][8];
    int m0 = blockIdx.x * 8;
    int tid = threadIdx.x;
    for (int s = tid; s < DT_RANK * 8; s += 256) {
        int r = s >> 3, rr = s & 7;
        sw[r][rr] = wdt[r * D_MODEL + m0 + rr];
    }
    __syncthreads();
    float acc[8][4] = {};
    for (int r = 0; r < DT_RANK; r++) {
        float tv0 = Tt[r * D_MODEL + tid];
        float tv1 = Tt[r * D_MODEL + tid + 256];
        float tv2 = Tt[r * D_MODEL + tid + 512];
        float tv3 = Tt[r * D_MODEL + tid + 768];
#pragma unroll
        for (int rr = 0; rr < 8; rr++) {
            float wv = sw[r][rr];
            acc[rr][0] = fmaf(wv, tv0, acc[rr][0]);
            acc[rr][1] = fmaf(wv, tv1, acc[rr][1]);
            acc[rr][2] = fmaf(wv, tv2, acc[rr][2]);
            acc[rr][3] = fmaf(wv, tv3, acc[rr][3]);
        }
    }
#pragma unroll
    for (int rr = 0; rr < 8; rr++)
#pragma unroll
        for (int i = 0; i < 4; i++)
            bt[(D_MODEL + m0 + rr) * D_MODEL + tid + i * 256] = f2bf(acc[rr][i]);
}

// ---------- big GEMM: 128x128 tile, BK=64, dbuf, XOR-swizzled LDS, grid 512 (2/CU) ----------
__global__ void __launch_bounds__(256) k_gemm_big(const unsigned short* __restrict__ xb,
                                                  const unsigned short* __restrict__ bt,
                                                  const float* __restrict__ bdt,
                                                  unsigned short* __restrict__ xinb,
                                                  unsigned short* __restrict__ dtb) {
    __shared__ unsigned short sA[2][128 * 64];
    __shared__ unsigned short sB[2][128 * 64];
    int bid = blockIdx.x;
    int m0 = (bid & 31) * 128;
    int nt = bid >> 5;  // 0..15
    int n0 = nt * 128;
    int t = threadIdx.x;
    int lane = t & 63;
    int w = t >> 6;
    int wm = (w >> 1) * 64, wn = (w & 1) * 64;
    int c = lane & 15, q = lane >> 4;

    const unsigned short* gA[4];
    const unsigned short* gB[4];
#pragma unroll
    for (int L = 0; L < 4; L++) {
        int s = L * 256 + t;
        int row = s >> 3, ch = (s & 7) ^ (row & 7);
        gA[L] = xb + (m0 + row) * D_MODEL + ch * 8;
        gB[L] = bt + (n0 + row) * D_MODEL + ch * 8;
    }

    f32x4 acc[4][4] = {};
    {
        char* la = (char*)&sA[0][0] + w * 1024;
        char* lb = (char*)&sB[0][0] + w * 1024;
#pragma unroll
        for (int L = 0; L < 4; L++) {
            gload16(gA[L], la + L * 4096);
            gload16(gB[L], lb + L * 4096);
        }
    }
    int cur = 0;
    for (int it = 0; it < 16; it++) {
        __syncthreads();
        if (it + 1 < 16) {
            int kn = (it + 1) * 64;
            char* la = (char*)&sA[cur ^ 1][0] + w * 1024;
            char* lb = (char*)&sB[cur ^ 1][0] + w * 1024;
#pragma unroll
            for (int L = 0; L < 4; L++) {
                gload16(gA[L] + kn, la + L * 4096);
                gload16(gB[L] + kn, lb + L * 4096);
            }
        }
#pragma unroll
        for (int kk = 0; kk < 2; kk++) {
            int perm = (((kk << 2) | q) ^ (c & 7)) << 3;
            bf16x8 af[4], bfr[4];
#pragma unroll
            for (int i = 0; i < 4; i++)
                af[i] = *reinterpret_cast<const bf16x8*>(&sA[cur][(wm + i * 16 + c) * 64 + perm]);
#pragma unroll
            for (int j = 0; j < 4; j++)
                bfr[j] = *reinterpret_cast<const bf16x8*>(&sB[cur][(wn + j * 16 + c) * 64 + perm]);
#pragma unroll
            for (int i = 0; i < 4; i++)
#pragma unroll
                for (int j = 0; j < 4; j++)
                    acc[i][j] = __builtin_amdgcn_mfma_f32_16x16x32_bf16(af[i], bfr[j], acc[i][j], 0, 0, 0);
        }
        cur ^= 1;
    }

    if (nt < 8) {
#pragma unroll
        for (int i = 0; i < 4; i++) {
            int row = m0 + wm + i * 16 + q * 4;
#pragma unroll
            for (int j = 0; j < 4; j++) {
                int col = n0 + wn + j * 16 + c;
#pragma unroll
                for (int r = 0; r < 4; r++)
                    xinb[(row + r) * D_MODEL + col] = f2bf(acc[i][j][r]);
            }
        }
    } else {
#pragma unroll
        for (int i = 0; i < 4; i++) {
            int row = m0 + wm + i * 16 + q * 4;
#pragma unroll
            for (int j = 0; j < 4; j++) {
                int dcol = n0 + wn + j * 16 + c - D_MODEL;
                float bv = bdt[dcol];
#pragma unroll
                for (int r = 0; r < 4; r++) {
                    float xv = acc[i][j][r] + bv;
                    float sp = fmaxf(xv, 0.f) + __logf(1.f + __expf(-fabsf(xv)));
                    dtb[(row + r) * D_MODEL + dcol] = f2bf(sp * 0.099f + 0.001f);
                }
            }
        }
    }
}

// ---------- BCW GEMM: bcp = x_in @ wxBC^T ; wpp = (dt*u) @ anegT^T ; direct-global MFMA ----------
__global__ void __launch_bounds__(256) k_bcw(const unsigned short* __restrict__ xinb,
                                             const unsigned short* __restrict__ dtb,
                                             const unsigned short* __restrict__ wxBC,
                                             const unsigned short* __restrict__ anegT,
                                             float* __restrict__ bcp,
                                             float* __restrict__ wpp) {
    int bid = blockIdx.x;  // 128 = 32 mtiles x 4 ksplit
    int m0 = (bid & 31) * 128;
    int ks = bid >> 5;
    int kbase = ks * 256;
    int t = threadIdx.x;
    int lane = t & 63, w = t >> 6;
    int c = lane & 15, q = lane >> 4;
    int mw = m0 + w * 32;
    f32x4 accb[2][2] = {};
    f32x4 accw[2] = {};
    const unsigned short* pa0 = xinb + (mw + c) * D_MODEL + kbase + q * 8;
    const unsigned short* pa1 = pa0 + 16 * D_MODEL;
    const unsigned short* pt0 = dtb + (mw + c) * D_MODEL + kbase + q * 8;
    const unsigned short* pt1 = pt0 + 16 * D_MODEL;
    const unsigned short* pb0 = wxBC + c * D_MODEL + kbase + q * 8;
    const unsigned short* pb1 = pb0 + 16 * D_MODEL;
    const unsigned short* pA = anegT + c * D_MODEL + kbase + q * 8;
#pragma unroll
    for (int k0 = 0; k0 < 256; k0 += 32) {
        bf16x8 a0 = *reinterpret_cast<const bf16x8*>(pa0 + k0);
        bf16x8 a1 = *reinterpret_cast<const bf16x8*>(pa1 + k0);
        bf16x8 t0 = *reinterpret_cast<const bf16x8*>(pt0 + k0);
        bf16x8 t1 = *reinterpret_cast<const bf16x8*>(pt1 + k0);
        bf16x8 b0 = *reinterpret_cast<const bf16x8*>(pb0 + k0);
        bf16x8 b1 = *reinterpret_cast<const bf16x8*>(pb1 + k0);
        bf16x8 bA = *reinterpret_cast<const bf16x8*>(pA + k0);
        bf16x8 g0, g1;
#pragma unroll
        for (int e = 0; e < 8; e++) {
            g0[e] = (__bf16)((float)t0[e] * (float)a0[e]);
            g1[e] = (__bf16)((float)t1[e] * (float)a1[e]);
        }
        accb[0][0] = __builtin_amdgcn_mfma_f32_16x16x32_bf16(a0, b0, accb[0][0], 0, 0, 0);
        accb[0][1] = __builtin_amdgcn_mfma_f32_16x16x32_bf16(a0, b1, accb[0][1], 0, 0, 0);
        accb[1][0] = __builtin_amdgcn_mfma_f32_16x16x32_bf16(a1, b0, accb[1][0], 0, 0, 0);
        accb[1][1] = __builtin_amdgcn_mfma_f32_16x16x32_bf16(a1, b1, accb[1][1], 0, 0, 0);
        accw[0] = __builtin_amdgcn_mfma_f32_16x16x32_bf16(g0, bA, accw[0], 0, 0, 0);
        accw[1] = __builtin_amdgcn_mfma_f32_16x16x32_bf16(g1, bA, accw[1], 0, 0, 0);
    }
    // C/D: col = c, row = q*4 + r
#pragma unroll
    for (int i = 0; i < 2; i++) {
        int row = mw + i * 16 + q * 4;
#pragma unroll
        for (int j = 0; j < 2; j++) {
            int p = j * 16 + c;
#pragma unroll
            for (int r = 0; r < 4; r++)
                bcp[(ks * M_TOTAL + row + r) * 32 + p] = accb[i][j][r];
        }
#pragma unroll
        for (int r = 0; r < 4; r++)
            wpp[(ks * M_TOTAL + row + r) * 16 + c] = accw[i][r];
    }
}

// ---------- finalize: bc = sum_ks bcp ; winp = bc[:, :16] * sum_ks wpp ----------
__global__ void __launch_bounds__(256) k_fin(const float* __restrict__ bcp,
                                             const float* __restrict__ wpp,
                                             float* __restrict__ bc,
                                             float* __restrict__ winp) {
    int idx = blockIdx.x * 256 + threadIdx.x;  // 131072
    int row = idx >> 5, p = idx & 31;
    float s = bcp[row * 32 + p] + bcp[(M_TOTAL + row) * 32 + p] +
              bcp[(2 * M_TOTAL + row) * 32 + p] + bcp[(3 * M_TOTAL + row) * 32 + p];
    bc[row * 32 + p] = s;
    if (p < 16) {
        float wsum = wpp[row * 16 + p] + wpp[(M_TOTAL + row) * 16 + p] +
                     wpp[(2 * M_TOTAL + row) * 16 + p] + wpp[(3 * M_TOTAL + row) * 16 + p];
        winp[row * 16 + p] = s * wsum;
    }
}

// ---------- scan phase 1: chunk-local scan -> h_loc, dtsum (vector staging) ----------
__global__ void __launch_bounds__(256) k_scan1(const unsigned short* __restrict__ dtb,
                                               const float* __restrict__ winp,
                                               const float* __restrict__ aneg,
                                               float* __restrict__ h_loc,
                                               float* __restrict__ dtsum) {
    __shared__ unsigned short s_dt[16][256];
    __shared__ float s_w[16][16];
    int dc = blockIdx.x & 3;
    int c = (blockIdx.x >> 2) & (CHUNKS - 1);
    int b = blockIdx.x >> 8;
    int tid = threadIdx.x;
    int d = dc * 256 + tid;
    float Ad[16];
    const float4* ar = reinterpret_cast<const float4*>(aneg + d * 16);
#pragma unroll
    for (int j = 0; j < 4; j++) {
        float4 a4 = ar[j];
        Ad[4 * j + 0] = a4.x; Ad[4 * j + 1] = a4.y;
        Ad[4 * j + 2] = a4.z; Ad[4 * j + 3] = a4.w;
    }
    float h[16];
#pragma unroll
    for (int n = 0; n < 16; n++) h[n] = 0.f;
    float dts = 0.f;

    int r8 = tid >> 5, col8 = (tid & 31) * 8;
    for (int t0 = 0; t0 < CLEN; t0 += 16) {
        __syncthreads();
        int rowbase = b * SEQ + c * CLEN + t0;
        *reinterpret_cast<uint4*>(&s_dt[r8][col8]) =
            *reinterpret_cast<const uint4*>(dtb + (rowbase + r8) * D_MODEL + dc * 256 + col8);
        *reinterpret_cast<uint4*>(&s_dt[8 + r8][col8]) =
            *reinterpret_cast<const uint4*>(dtb + (rowbase + 8 + r8) * D_MODEL + dc * 256 + col8);
        {
            int r = tid >> 4, n = tid & 15;
            s_w[r][n] = winp[(rowbase + r) * 16 + n];
        }
        __syncthreads();
        for (int r = 0; r < 16; r++) {
            float dtv = bf2f(s_dt[r][tid]);
            dts += dtv;
#pragma unroll
            for (int n = 0; n < 16; n++) {
                float ba = __expf(dtv * Ad[n]);
                h[n] = fmaf(ba, h[n], s_w[r][n]);
            }
        }
    }
    int base = ((b * CHUNKS + c) * D_MODEL + d) * 16;
#pragma unroll
    for (int j = 0; j < 4; j++) {
        f32x4 v = {h[4 * j], h[4 * j + 1], h[4 * j + 2], h[4 * j + 3]};
        *reinterpret_cast<f32x4*>(h_loc + base + 4 * j) = v;
    }
    dtsum[(b * CHUNKS + c) * D_MODEL + d] = dts;
}

// ---------- scan phase 2: combine chunks ----------
__global__ void __launch_bounds__(256) k_scan2(float* __restrict__ h_inout,
                                               const float* __restrict__ dtsum,
                                               const float* __restrict__ aneg) {
    int idx = blockIdx.x * 256 + threadIdx.x;
    int n = idx & 15;
    int d = (idx >> 4) & (D_MODEL - 1);
    int b = idx >> 14;
    float A = aneg[d * 16 + n];
    float H = 0.f;
    int off = (b * CHUNKS) * D_MODEL + d;
    float hl = h_inout[off * 16 + n];
    float ds = dtsum[off];
    for (int c = 0; c < CHUNKS; c++) {
        int off2 = off + D_MODEL;
        float hl_n = 0.f, ds_n = 0.f;
        if (c + 1 < CHUNKS) { hl_n = h_inout[off2 * 16 + n]; ds_n = dtsum[off2]; }
        float P = __expf(ds * A);
        h_inout[off * 16 + n] = H;
        H = fmaf(P, H, hl);
        hl = hl_n; ds = ds_n; off = off2;
    }
}

// ---------- scan phase 3: chunk scan from H_in; emit y (vector staging) ----------
__global__ void __launch_bounds__(256) k_scan3(const unsigned short* __restrict__ dtb,
                                               const unsigned short* __restrict__ xinb,
                                               const float* __restrict__ winp,
                                               const float* __restrict__ bc,
                                               const float* __restrict__ aneg,
                                               const float* __restrict__ dp,
                                               const float* __restrict__ H_in,
                                               float* __restrict__ out) {
    __shared__ unsigned short s_dt[16][256], s_u[16][256];
    __shared__ float s_w[16][16], s_c[16][16];
    int dc = blockIdx.x & 3;
    int c = (blockIdx.x >> 2) & (CHUNKS - 1);
    int b = blockIdx.x >> 8;
    int tid = threadIdx.x;
    int d = dc * 256 + tid;
    float Ad[16];
    const float4* ar = reinterpret_cast<const float4*>(aneg + d * 16);
#pragma unroll
    for (int j = 0; j < 4; j++) {
        float4 a4 = ar[j];
        Ad[4 * j + 0] = a4.x; Ad[4 * j + 1] = a4.y;
        Ad[4 * j + 2] = a4.z; Ad[4 * j + 3] = a4.w;
    }
    float Dpd = dp[d];
    float h[16];
    int base = ((b * CHUNKS + c) * D_MODEL + d) * 16;
#pragma unroll
    for (int j = 0; j < 4; j++) {
        f32x4 v = *reinterpret_cast<const f32x4*>(H_in + base + 4 * j);
        h[4 * j] = v[0]; h[4 * j + 1] = v[1]; h[4 * j + 2] = v[2]; h[4 * j + 3] = v[3];
    }

    int r8 = tid >> 5, col8 = (tid & 31) * 8;
    for (int t0 = 0; t0 < CLEN; t0 += 16) {
        __syncthreads();
        int rowbase = b * SEQ + c * CLEN + t0;
        *reinterpret_cast<uint4*>(&s_dt[r8][col8]) =
            *reinterpret_cast<const uint4*>(dtb + (rowbase + r8) * D_MODEL + dc * 256 + col8);
        *reinterpret_cast<uint4*>(&s_dt[8 + r8][col8]) =
            *reinterpret_cast<const uint4*>(dtb + (rowbase + 8 + r8) * D_MODEL + dc * 256 + col8);
        *reinterpret_cast<uint4*>(&s_u[r8][col8]) =
            *reinterpret_cast<const uint4*>(xinb + (rowbase + r8) * D_MODEL + dc * 256 + col8);
        *reinterpret_cast<uint4*>(&s_u[8 + r8][col8]) =
            *reinterpret_cast<const uint4*>(xinb + (rowbase + 8 + r8) * D_MODEL + dc * 256 + col8);
        {
            int r = tid >> 4, n = tid & 15;
            s_w[r][n] = winp[(rowbase + r) * 16 + n];
            s_c[r][n] = bc[(rowbase + r) * 32 + 16 + n];
        }
        __syncthreads();
        for (int r = 0; r < 16; r++) {
            float dtv = bf2f(s_dt[r][tid]), uv = bf2f(s_u[r][tid]);
            float y = Dpd * uv;
#pragma unroll
            for (int n = 0; n < 16; n++) {
                float ba = __expf(dtv * Ad[n]);
                h[n] = fmaf(ba, h[n], s_w[r][n]);
                y = fmaf(h[n], s_c[r][n], y);
            }
            out[(rowbase + r) * D_MODEL + d] = y;
        }
    }
}

extern "C" void kernel_launch(void* const* d_in, const int* in_sizes, int n_in,
                              void* d_out, int out_size, void* d_ws, size_t ws_size,
                              hipStream_t stream) {
    const float* x     = (const float*)d_in[0];
    const float* w_in  = (const float*)d_in[1];
    const float* w_x   = (const float*)d_in[2];
    const float* w_dt  = (const float*)d_in[3];
    const float* b_dt  = (const float*)d_in[4];
    const float* A_log = (const float*)d_in[5];
    const float* Dp    = (const float*)d_in[6];
    float* out = (float*)d_out;

    char* ws = (char*)d_ws;
    // footprint capped below proven-safe 39124992 B
    unsigned short* xb   = (unsigned short*)(ws + 0);          // 8 MB (dead after gemm)
    unsigned short* bt   = (unsigned short*)(ws + 8388608);    // 4 MB (dead after gemm)
    float* Tt            = (float*)(ws + 12845056);            // 256 KB
    float* aneg          = (float*)(ws + 13107200);            // 64 KB
    float* bc            = (float*)(ws + 13172736);            // 512 KB
    float* winp          = (float*)(ws + 13697024);            // 256 KB
    unsigned short* xinb = (unsigned short*)(ws + 13959168);   // 8 MB
    unsigned short* dtb  = (unsigned short*)(ws + 22347776);   // 8 MB bf16 -> ends 30736384
    // prep-phase overlays of dtb region (dead until gemm writes dtb):
    unsigned short* wib  = (unsigned short*)(ws + 22347776);   // 2 MB   bf16 w_in row-major
    unsigned short* wxT  = (unsigned short*)(ws + 24444928);   // 128 KB bf16 w_x[:, :64]^T
    float* Cp            = (float*)(ws + 24707072);            // 1 MB   K-split partials
    // survive gemm (after dtb):
    unsigned short* wxBC = (unsigned short*)(ws + 30736384);   // 64 KB  bf16 w_x[:,64:96]^T
    float* bcp           = (float*)(ws + 30801920);            // 2 MB   BC K-split partials
    float* wpp           = (float*)(ws + 32899072);            // 1 MB   winp K-split partials
    unsigned short* anegT= (unsigned short*)(ws + 33947648);   // 32 KB  bf16 aneg^T [n][d] -> ends 33980416
    // scan-phase overlays of dead xb/bt regions:
    float* h_loc         = (float*)(ws + 0);                   // 8 MB  [b][c][d][n]
    float* dtsum         = (float*)(ws + 8388608);             // 512 KB [b][c][d]

    k_setup<<<6592, 256, 0, stream>>>(x, w_in, w_x, A_log, xb, wib, bt, wxT, wxBC, aneg, anegT);
    k_prepgemm<<<32, 256, 0, stream>>>(wxT, wib, Cp);
    k_prepreduce<<<256, 256, 0, stream>>>(Cp, Tt);
    k_prep2<<<128, 256, 0, stream>>>(w_dt, Tt, bt);
    k_gemm_big<<<512, 256, 0, stream>>>(xb, bt, b_dt, xinb, dtb);
    k_bcw<<<128, 256, 0, stream>>>(xinb, dtb, wxBC, anegT, bcp, wpp);
    k_fin<<<512, 256, 0, stream>>>(bcp, wpp, bc, winp);
    k_scan1<<<BATCH * CHUNKS * 4, 256, 0, stream>>>(dtb, winp, aneg, h_loc, dtsum);
    k_scan2<<<128, 256, 0, stream>>>(h_loc, dtsum, aneg);
    k_scan3<<<BATCH * CHUNKS * 4, 256, 0, stream>>>(dtb, xinb, winp, bc, aneg, Dp, h_loc, out);
}